// Round 2
// baseline (419.064 us; speedup 1.0000x reference)
//
#include <hip/hip_runtime.h>

#define HW   (256*256)        // 65536
#define VOL  (64*HW)          // 4194304 per batch volume
#define NTOT (4ull*VOL)
#define C1v  1e-4f
#define C2v  9e-4f
#define EPSv 1e-8f

typedef float    f4 __attribute__((ext_vector_type(4)));
typedef _Float16 h4 __attribute__((ext_vector_type(4)));

// ws layout:
// [0      .. 63]     : w[11] float (1D separable weights)
// [64     .. 16447]  : partials[2048] double
// [16640  .. ]       : field volumes, fp16: 5*VOL*2 bytes per resident batch

__global__ void init_weights(const float* __restrict__ k3, float* __restrict__ w) {
    int i = threadIdx.x;
    if (i < 11) {
        float s = 0.f;
        for (int t = 0; t < 121; ++t) s += k3[i * 121 + t];
        w[i] = s;   // = g[i]/sum(g) exactly (k3 is separable)
    }
}

// Pass 1: D-conv of the 5 fields (x, y, x^2, y^2, xy), direct form.
// grid: (HW/1024, 64, nb) x 256 threads; each thread = one float4 column at depth d.
__global__ __launch_bounds__(256) void dblur(
    const float* __restrict__ x, const float* __restrict__ y,
    const float* __restrict__ w11, _Float16* __restrict__ fields, int b0)
{
    const int d  = blockIdx.y;
    const int b  = b0 + blockIdx.z;
    const int q  = blockIdx.x * 256 + threadIdx.x;   // float4 index in slice, 0..16383
    const int HW4 = HW / 4;

    float wl[11];
#pragma unroll
    for (int t = 0; t < 11; ++t) wl[t] = w11[t];

    const f4* xs = (const f4*)(x + (size_t)b * VOL);
    const f4* ys = (const f4*)(y + (size_t)b * VOL);

    f4 aX = {0,0,0,0}, aY = {0,0,0,0}, aXX = {0,0,0,0}, aYY = {0,0,0,0}, aXY = {0,0,0,0};
#pragma unroll
    for (int k = 0; k < 11; ++k) {
        int dd = d - 5 + k;
        if (dd >= 0 && dd < 64) {       // uniform branch (d uniform per block)
            f4 xv = xs[(size_t)dd * HW4 + q];
            f4 yv = ys[(size_t)dd * HW4 + q];
            float wk = wl[k];
            aX  += wk * xv;
            aY  += wk * yv;
            aXX += wk * (xv * xv);
            aYY += wk * (yv * yv);
            aXY += wk * (xv * yv);
        }
    }

    h4* out = (h4*)(fields + (size_t)(b - b0) * 5 * VOL);
    const size_t V4 = VOL / 4;
    size_t oi = (size_t)d * HW4 + q;
    out[oi]          = __builtin_convertvector(aX,  h4);
    out[V4 + oi]     = __builtin_convertvector(aY,  h4);
    out[2*V4 + oi]   = __builtin_convertvector(aXX, h4);
    out[3*V4 + oi]   = __builtin_convertvector(aYY, h4);
    out[4*V4 + oi]   = __builtin_convertvector(aXY, h4);
}

// Pass 2: fused H-conv (register rings) + W-conv (LDS row) + SSIM + reduction.
// grid: (8, 64, nb) x 256 threads. Block = one d-slice, 32 output rows, full W=256.
__global__ __launch_bounds__(256) void hw_ssim(
    const _Float16* __restrict__ fields, const float* __restrict__ w11,
    double* __restrict__ partials, int b0)
{
    __shared__ float sh[2][5][272];   // double-buffered staged row, 266 used

    const int hq  = blockIdx.x;       // 0..7 -> 32-row chunk
    const int d   = blockIdx.y;
    const int bz  = blockIdx.z;
    const int b   = b0 + bz;
    const int tid = threadIdx.x;      // owns output column tid
    const int h0  = hq * 32;

    float wl[11];
#pragma unroll
    for (int t = 0; t < 11; ++t) wl[t] = w11[t];

    const _Float16* fb = fields + (size_t)bz * 5 * VOL + (size_t)d * HW;

    float rX[11], rY[11], rXX[11], rYY[11], rXY[11];
    float acc = 0.f;

    auto stage = [&](int s) {         // stage input row r = h0-5+s into sh[s&1]
        int r = h0 - 5 + s;
        bool rv = (r >= 0) && (r < 256);
#pragma unroll
        for (int f = 0; f < 5; ++f) {
            int gc0 = tid - 5;
            float v0 = 0.f;
            if (rv && gc0 >= 0) v0 = (float)fb[(size_t)f * VOL + r * 256 + gc0];
            sh[s & 1][f][tid] = v0;
            if (tid < 10) {
                int gc1 = tid + 251;  // (tid+256)-5
                float v1 = 0.f;
                if (rv && gc1 < 256) v1 = (float)fb[(size_t)f * VOL + r * 256 + gc1];
                sh[s & 1][f][tid + 256] = v1;
            }
        }
    };

    stage(0);
    __syncthreads();

    for (int ch = 0; ch < 4; ++ch) {          // 42 steps total, chunked by 11
#pragma unroll
        for (int u = 0; u < 11; ++u) {
            const int s = ch * 11 + u;
            if (s < 42) {                      // uniform guard
                if (s + 1 < 42) stage(s + 1);  // prefetch next row into other buffer

                float vX = 0, vY = 0, vXX = 0, vYY = 0, vXY = 0;
#pragma unroll
                for (int k = 0; k < 11; ++k) {
                    float wk = wl[k];
                    vX  += wk * sh[s & 1][0][tid + k];
                    vY  += wk * sh[s & 1][1][tid + k];
                    vXX += wk * sh[s & 1][2][tid + k];
                    vYY += wk * sh[s & 1][3][tid + k];
                    vXY += wk * sh[s & 1][4][tid + k];
                }
                rX[u] = vX; rY[u] = vY; rXX[u] = vXX; rYY[u] = vYY; rXY[u] = vXY;

                if (s >= 10) {                 // emit output row h0 + (s-10)
                    float mX = 0, mY = 0, cXX = 0, cYY = 0, cXY = 0;
#pragma unroll
                    for (int t = 0; t < 11; ++t) {
                        const int j = (u + 1 + t) % 11;   // static
                        float wt = wl[t];
                        mX  += wt * rX[j];
                        mY  += wt * rY[j];
                        cXX += wt * rXX[j];
                        cYY += wt * rYY[j];
                        cXY += wt * rXY[j];
                    }
                    float mx2 = mX * mX, my2 = mY * mY, mxy = mX * mY;
                    float sx2 = cXX - mx2, sy2 = cYY - my2, sxy = cXY - mxy;
                    float num = (2.f * mxy + C1v) * (2.f * sxy + C2v);
                    float den = (mx2 + my2 + C1v) * (sx2 + sy2 + C2v);
                    acc += num / (den + EPSv);
                }
                __syncthreads();
            }
        }
    }

    // block reduction (deterministic)
    for (int off = 32; off; off >>= 1) acc += __shfl_down(acc, off, 64);
    __shared__ float wsum[4];
    int lane = tid & 63, wid = tid >> 6;
    if (lane == 0) wsum[wid] = acc;
    __syncthreads();
    if (tid == 0) {
        float ssum = wsum[0] + wsum[1] + wsum[2] + wsum[3];
        partials[(size_t)b * 512 + d * 8 + hq] = (double)ssum;
    }
}

__global__ void finalize(const double* __restrict__ partials, float* __restrict__ out, int n) {
    __shared__ double sh[256];
    double s = 0.0;
    for (int i = threadIdx.x; i < n; i += 256) s += partials[i];
    sh[threadIdx.x] = s;
    __syncthreads();
    for (int stride = 128; stride; stride >>= 1) {
        if (threadIdx.x < stride) sh[threadIdx.x] += sh[threadIdx.x + stride];
        __syncthreads();
    }
    if (threadIdx.x == 0) out[0] = 1.0f - (float)(sh[0] / (double)NTOT);
}

extern "C" void kernel_launch(void* const* d_in, const int* in_sizes, int n_in,
                              void* d_out, int out_size, void* d_ws, size_t ws_size,
                              hipStream_t stream) {
    const float* x  = (const float*)d_in[0];
    const float* y  = (const float*)d_in[1];
    const float* k3 = (const float*)d_in[2];
    float* out = (float*)d_out;

    char* ws = (char*)d_ws;
    float*     w11      = (float*)ws;
    double*    partials = (double*)(ws + 64);
    _Float16*  fields   = (_Float16*)(ws + 16640);

    const size_t perBatch = (size_t)5 * VOL * 2;   // fp16 fields per batch
    const bool all4 = ws_size >= 16640 + 4 * perBatch;

    init_weights<<<1, 64, 0, stream>>>(k3, w11);

    if (all4) {
        dblur  <<<dim3(64, 64, 4), 256, 0, stream>>>(x, y, w11, fields, 0);
        hw_ssim<<<dim3(8, 64, 4),  256, 0, stream>>>(fields, w11, partials, 0);
    } else {
        for (int b = 0; b < 4; ++b) {
            dblur  <<<dim3(64, 64, 1), 256, 0, stream>>>(x, y, w11, fields, b);
            hw_ssim<<<dim3(8, 64, 1),  256, 0, stream>>>(fields, w11, partials, b);
        }
    }

    finalize<<<1, 256, 0, stream>>>(partials, out, 2048);
}